// Round 1
// baseline (476.998 us; speedup 1.0000x reference)
//
#include <hip/hip_runtime.h>
#include <cstdint>
#include <cstddef>

#define NH 8
#define DH 64
#define DM 512
#define CTX 64
#define BB 2
#define QL 2048
#define TT (QL + CTX - 1)   // 2111
#define HDIM (NH * DH)      // 512
#define KVN (2 * HDIM)      // 1024

// ---------------------------------------------------------------------------
// Generic fp32 tiled GEMM:  C[M,N] = A_rows @ Bw[K,N] (+ bias[n])
// A row m maps to global row:  (m / rpb) * bstride + roff + (m % rpb)
// (expresses x[:, C-1:] batch slicing without a copy)
// Tile 64x64, BK=16, 256 threads (16x16), 4x4 per-thread microtile.
// ---------------------------------------------------------------------------
__global__ __launch_bounds__(256) void gemm_bias_kernel(
    const float* __restrict__ A, const float* __restrict__ Bw,
    const float* __restrict__ bias, float* __restrict__ C,
    int M, int N, int K, int rpb, int bstride, int roff)
{
    __shared__ float As[16][68];   // [kk][m] padded, rows 272B (16B aligned)
    __shared__ float Bs[16][68];   // [kk][n]

    const int tx = threadIdx.x;          // 0..15
    const int ty = threadIdx.y;          // 0..15
    const int tid = ty * 16 + tx;
    const int m0 = blockIdx.y * 64;
    const int n0 = blockIdx.x * 64;

    // A staging: this thread loads a float4 from row (m0 + tid/4), k = kt + (tid%4)*4
    const int mloc = tid >> 2;                  // 0..63
    const int ka4  = (tid & 3) * 4;             // 0,4,8,12
    const int mrow = m0 + mloc;
    const float* aptr = nullptr;
    if (mrow < M) {
        long grow = (long)(mrow / rpb) * bstride + roff + (mrow % rpb);
        aptr = A + grow * (long)K + ka4;
    }

    // B staging: this thread loads a float4 from row kt + tid/16, col n0 + (tid%16)*4
    const int kb  = tid >> 4;                   // 0..15
    const int nb4 = (tid & 15) * 4;             // 0..60
    const float* bptr = Bw + (size_t)kb * N + n0 + nb4;

    float acc[4][4] = {};

    for (int kt = 0; kt < K; kt += 16) {
        float4 av = make_float4(0.f, 0.f, 0.f, 0.f);
        if (aptr) av = *(const float4*)(aptr + kt);
        float4 bv = *(const float4*)(bptr + (size_t)kt * N);

        __syncthreads();   // protect previous iteration's LDS reads
        As[ka4 + 0][mloc] = av.x;
        As[ka4 + 1][mloc] = av.y;
        As[ka4 + 2][mloc] = av.z;
        As[ka4 + 3][mloc] = av.w;
        *(float4*)&Bs[kb][nb4] = bv;
        __syncthreads();

#pragma unroll
        for (int kk = 0; kk < 16; kk++) {
            float4 a = *(const float4*)&As[kk][ty * 4];
            float4 b = *(const float4*)&Bs[kk][tx * 4];
            acc[0][0] += a.x * b.x; acc[0][1] += a.x * b.y; acc[0][2] += a.x * b.z; acc[0][3] += a.x * b.w;
            acc[1][0] += a.y * b.x; acc[1][1] += a.y * b.y; acc[1][2] += a.y * b.z; acc[1][3] += a.y * b.w;
            acc[2][0] += a.z * b.x; acc[2][1] += a.z * b.y; acc[2][2] += a.z * b.z; acc[2][3] += a.z * b.w;
            acc[3][0] += a.w * b.x; acc[3][1] += a.w * b.y; acc[3][2] += a.w * b.z; acc[3][3] += a.w * b.w;
        }
    }

    // epilogue
    float4 bia = make_float4(0.f, 0.f, 0.f, 0.f);
    if (bias) bia = *(const float4*)(bias + n0 + tx * 4);
#pragma unroll
    for (int i = 0; i < 4; i++) {
        int m = m0 + ty * 4 + i;
        if (m < M) {
            float4 o;
            o.x = acc[i][0] + bia.x;
            o.y = acc[i][1] + bia.y;
            o.z = acc[i][2] + bia.z;
            o.w = acc[i][3] + bia.w;
            *(float4*)&C[(size_t)m * N + n0 + tx * 4] = o;
        }
    }
}

// ---------------------------------------------------------------------------
// Sliding-window relative attention.
// One wave (64 lanes) per (b, h, q). lane = window position c for scores,
// lane = head-dim d for the output accumulation.
// ---------------------------------------------------------------------------
__global__ __launch_bounds__(256) void attn_kernel(
    const float* __restrict__ kv,    // [B*T, 1024] (k | v)
    const float* __restrict__ hq,    // [B*QL, 512]
    const float* __restrict__ hr,    // [CTX, 512]
    const float* __restrict__ x,     // [B*T, 512] (for pad mask)
    float* __restrict__ attn_out)    // [B*QL, 512]
{
    const int widx = threadIdx.x >> 6;          // wave in block (0..3)
    const int lane = threadIdx.x & 63;
    const int wv = blockIdx.x * 4 + widx;       // 0 .. B*QL*NH-1
    const int h = wv & (NH - 1);
    const int q = (wv >> 3) & (QL - 1);
    const int b = wv >> 14;

    __shared__ float sw[4][64];

    const float* hq_row = hq + ((size_t)(b * QL + q) * HDIM + h * DH);
    const int t = q + lane;                                    // k/v time index
    const float* k_row  = kv + ((size_t)(b * TT + t) * KVN + h * DH);
    const float* hr_row = hr + ((size_t)lane * HDIM + h * DH);

    float s = 0.f;
#pragma unroll
    for (int d = 0; d < DH; d += 4) {
        float4 a  = *(const float4*)(hq_row + d);
        float4 kk = *(const float4*)(k_row + d);
        float4 rr = *(const float4*)(hr_row + d);
        s += a.x * (kk.x + rr.x) + a.y * (kk.y + rr.y)
           + a.z * (kk.z + rr.z) + a.w * (kk.w + rr.w);
    }
    s *= 0.125f;   // 1/sqrt(64)

    // pad mask: positions t < CTX-1 masked if x[b,t,:] all zero
    if (q < CTX - 1) {            // wave-uniform fast skip
        if (t < CTX - 1) {
            const float* xr = x + (size_t)(b * TT + t) * DM;
            bool allz = true;
            for (int i = 0; i < DM && allz; i++) allz = (xr[i] == 0.f);
            if (allz) s = -1e30f;
        }
    }

    // wave softmax over 64 lanes
    float m = s;
#pragma unroll
    for (int off = 32; off > 0; off >>= 1) m = fmaxf(m, __shfl_xor(m, off, 64));
    float e = expf(s - m);
    float sum = e;
#pragma unroll
    for (int off = 32; off > 0; off >>= 1) sum += __shfl_xor(sum, off, 64);
    float w = e / sum;

    sw[widx][lane] = w;
    __syncthreads();

    // output: lane = d; coalesced v reads
    const float* v_base = kv + ((size_t)(b * TT + q) * KVN + HDIM + h * DH + lane);
    float acc = 0.f;
#pragma unroll
    for (int c = 0; c < CTX; c++) acc += sw[widx][c] * v_base[(size_t)c * KVN];

    attn_out[(size_t)(b * QL + q) * HDIM + h * DH + lane] = acc;
}

// ---------------------------------------------------------------------------
extern "C" void kernel_launch(void* const* d_in, const int* in_sizes, int n_in,
                              void* d_out, int out_size, void* d_ws, size_t ws_size,
                              hipStream_t stream)
{
    const float* x   = (const float*)d_in[0];   // [B,T,512]
    const float* r   = (const float*)d_in[1];   // [64,512]
    const float* Wkv = (const float*)d_in[2];   // [512,1024]
    const float* Wq  = (const float*)d_in[3];   // [512,512]
    const float* bq  = (const float*)d_in[4];   // [512]
    const float* Wr  = (const float*)d_in[5];   // [512,512]
    const float* Wo  = (const float*)d_in[6];   // [512,512]
    float* out = (float*)d_out;

    float* ws = (float*)d_ws;
    float* kv_ws   = ws;                                  // B*T*1024   = 4,323,328
    float* hq_ws   = kv_ws + (size_t)BB * TT * KVN;       // B*QL*512   = 2,097,152
    float* hr_ws   = hq_ws + (size_t)BB * QL * HDIM;      // 64*512     = 32,768
    float* attn_ws = hr_ws + (size_t)CTX * HDIM;          // B*QL*512   = 2,097,152

    dim3 blk(16, 16);

    // 1) kv = x @ Wkv      [4222 x 1024 x 512]
    {
        int M = BB * TT, N = KVN, K = DM;
        dim3 grid(N / 64, (M + 63) / 64);
        hipLaunchKernelGGL(gemm_bias_kernel, grid, blk, 0, stream,
                           x, Wkv, nullptr, kv_ws, M, N, K, M, 0, 0);
    }
    // 2) hq = x[:, 63:] @ Wq + bq   [4096 x 512 x 512]
    {
        int M = BB * QL, N = HDIM, K = DM;
        dim3 grid(N / 64, M / 64);
        hipLaunchKernelGGL(gemm_bias_kernel, grid, blk, 0, stream,
                           x, Wq, bq, hq_ws, M, N, K, QL, TT, CTX - 1);
    }
    // 3) hr = r @ Wr        [64 x 512 x 512]
    {
        int M = CTX, N = HDIM, K = DM;
        dim3 grid(N / 64, 1);
        hipLaunchKernelGGL(gemm_bias_kernel, grid, blk, 0, stream,
                           r, Wr, nullptr, hr_ws, M, N, K, M, 0, 0);
    }
    // 4) attention
    {
        int waves = BB * QL * NH;                  // 32768
        hipLaunchKernelGGL(attn_kernel, dim3(waves / 4), dim3(256), 0, stream,
                           kv_ws, hq_ws, hr_ws, x, attn_ws);
    }
    // 5) out = attn @ Wo    [4096 x 512 x 512]
    {
        int M = BB * QL, N = DM, K = HDIM;
        dim3 grid(N / 64, M / 64);
        hipLaunchKernelGGL(gemm_bias_kernel, grid, blk, 0, stream,
                           attn_ws, Wo, nullptr, out, M, N, K, M, 0, 0);
    }
}

// Round 2
// 424.762 us; speedup vs baseline: 1.1230x; 1.1230x over previous
//
#include <hip/hip_runtime.h>
#include <cstdint>
#include <cstddef>

#define NH 8
#define DH 64
#define DM 512
#define CTX 64
#define BB 2
#define QL 2048
#define TT (QL + CTX - 1)   // 2111
#define HDIM (NH * DH)      // 512
#define KVN (2 * HDIM)      // 1024

__device__ __forceinline__ float lane_bcast(float v, int l) {
    return __uint_as_float(__builtin_amdgcn_readlane(__float_as_uint(v), l));
}

// ---------------------------------------------------------------------------
// GEMM v2: C[M,N] = A_rows @ Bw[K,N] (+bias). Tile 128(M)x64(N), BK=16,
// 128 threads, 8x8 microtile. A row m -> global row (m/rpb)*bstride+roff+m%rpb.
// ---------------------------------------------------------------------------
__global__ __launch_bounds__(128) void gemm_bias_v2(
    const float* __restrict__ A, const float* __restrict__ Bw,
    const float* __restrict__ bias, float* __restrict__ C,
    int M, int N, int K, int rpb, int bstride, int roff)
{
    __shared__ float As[16][128];   // [kk][m]
    __shared__ float Bs[16][64];    // [kk][n]

    const int tid = threadIdx.x;
    const int tx = tid & 7;         // n micro: cols tx*8..+7
    const int ty = tid >> 3;        // m micro: rows ty*8..+7 (0..15)
    const int m0 = blockIdx.y * 128;
    const int n0 = blockIdx.x * 64;

    // A staging: 4 rows per thread (sm + it*32), k-quad sk
    const int sm = tid >> 2;          // 0..31
    const int sk = (tid & 3) * 4;     // 0,4,8,12
    // B staging: row bk, col-quad bn (+32 for second)
    const int bk = tid >> 3;          // 0..15
    const int bn = (tid & 7) * 4;     // 0..28

    const float* arow0 = nullptr; const float* arow1 = nullptr;
    const float* arow2 = nullptr; const float* arow3 = nullptr;
    {
        int m;
        m = m0 + sm;       if (m < M) arow0 = A + ((long)(m / rpb) * bstride + roff + (m % rpb)) * (long)K + sk;
        m = m0 + sm + 32;  if (m < M) arow1 = A + ((long)(m / rpb) * bstride + roff + (m % rpb)) * (long)K + sk;
        m = m0 + sm + 64;  if (m < M) arow2 = A + ((long)(m / rpb) * bstride + roff + (m % rpb)) * (long)K + sk;
        m = m0 + sm + 96;  if (m < M) arow3 = A + ((long)(m / rpb) * bstride + roff + (m % rpb)) * (long)K + sk;
    }
    const float* bptr0 = Bw + (size_t)bk * N + n0 + bn;
    const float* bptr1 = bptr0 + 32;

    float acc[8][8] = {};

    for (int kt = 0; kt < K; kt += 16) {
        float4 av0 = arow0 ? *(const float4*)(arow0 + kt) : make_float4(0.f,0.f,0.f,0.f);
        float4 av1 = arow1 ? *(const float4*)(arow1 + kt) : make_float4(0.f,0.f,0.f,0.f);
        float4 av2 = arow2 ? *(const float4*)(arow2 + kt) : make_float4(0.f,0.f,0.f,0.f);
        float4 av3 = arow3 ? *(const float4*)(arow3 + kt) : make_float4(0.f,0.f,0.f,0.f);
        float4 bv0 = *(const float4*)(bptr0 + (size_t)kt * N);
        float4 bv1 = *(const float4*)(bptr1 + (size_t)kt * N);

        __syncthreads();
        As[sk+0][sm]    = av0.x; As[sk+1][sm]    = av0.y; As[sk+2][sm]    = av0.z; As[sk+3][sm]    = av0.w;
        As[sk+0][sm+32] = av1.x; As[sk+1][sm+32] = av1.y; As[sk+2][sm+32] = av1.z; As[sk+3][sm+32] = av1.w;
        As[sk+0][sm+64] = av2.x; As[sk+1][sm+64] = av2.y; As[sk+2][sm+64] = av2.z; As[sk+3][sm+64] = av2.w;
        As[sk+0][sm+96] = av3.x; As[sk+1][sm+96] = av3.y; As[sk+2][sm+96] = av3.z; As[sk+3][sm+96] = av3.w;
        *(float4*)&Bs[bk][bn]      = bv0;
        *(float4*)&Bs[bk][bn + 32] = bv1;
        __syncthreads();

#pragma unroll
        for (int kk = 0; kk < 16; kk++) {
            float4 a0 = *(const float4*)&As[kk][ty*8];
            float4 a1 = *(const float4*)&As[kk][ty*8+4];
            float4 b0 = *(const float4*)&Bs[kk][tx*8];
            float4 b1 = *(const float4*)&Bs[kk][tx*8+4];
            float am[8] = {a0.x,a0.y,a0.z,a0.w,a1.x,a1.y,a1.z,a1.w};
            float bb[8] = {b0.x,b0.y,b0.z,b0.w,b1.x,b1.y,b1.z,b1.w};
#pragma unroll
            for (int i = 0; i < 8; i++)
#pragma unroll
                for (int j = 0; j < 8; j++)
                    acc[i][j] += am[i] * bb[j];
        }
    }

    float4 bia0 = make_float4(0.f,0.f,0.f,0.f), bia1 = bia0;
    if (bias) {
        bia0 = *(const float4*)(bias + n0 + tx*8);
        bia1 = *(const float4*)(bias + n0 + tx*8 + 4);
    }
#pragma unroll
    for (int i = 0; i < 8; i++) {
        int m = m0 + ty*8 + i;
        if (m < M) {
            float4 o0, o1;
            o0.x = acc[i][0] + bia0.x; o0.y = acc[i][1] + bia0.y;
            o0.z = acc[i][2] + bia0.z; o0.w = acc[i][3] + bia0.w;
            o1.x = acc[i][4] + bia1.x; o1.y = acc[i][5] + bia1.y;
            o1.z = acc[i][6] + bia1.z; o1.w = acc[i][7] + bia1.w;
            *(float4*)&C[(size_t)m * N + n0 + tx*8]     = o0;
            *(float4*)&C[(size_t)m * N + n0 + tx*8 + 4] = o1;
        }
    }
}

// ---------------------------------------------------------------------------
// Pad-mask precompute: maskv[b][t] = (x[b,t,:] all zero) ? -1e30 : 0, t<63.
// ---------------------------------------------------------------------------
__global__ __launch_bounds__(256) void mask_kernel(const float* __restrict__ x,
                                                   float* __restrict__ maskv)
{
    const int t = blockIdx.x;     // 0..62
    const int b = blockIdx.y;
    const int i = threadIdx.x;
    const float* row = x + ((size_t)(b * TT + t)) * DM;
    bool nz = (row[i] != 0.f) || (row[i + 256] != 0.f);
    __shared__ int anyflag;
    if (i == 0) anyflag = 0;
    __syncthreads();
    unsigned long long bal = __ballot(nz);
    if ((i & 63) == 0 && bal) atomicOr(&anyflag, 1);
    __syncthreads();
    if (i == 0) maskv[b * 64 + t] = anyflag ? 0.f : -1e30f;
}

// ---------------------------------------------------------------------------
// Fused sliding-window relative attention.
// Block = (b, h, 64-q tile), 256 threads = 4 waves, 16 q per wave, lane = c
// for scores / lane = d for PV.
// LDS: kT[d][t] 127x64 (reused as v[t][d]), hrT[d][c], weights w[qloc][c].
// ---------------------------------------------------------------------------
__global__ __launch_bounds__(256) void attn_fused(
    const float* __restrict__ kv,     // [B*T, 1024]
    const float* __restrict__ hq,     // [B*QL, 512]
    const float* __restrict__ hr,     // [CTX, 512]
    const float* __restrict__ maskv,  // [B, 64]
    float* __restrict__ attn_out)     // [B*QL, 512]
{
    __shared__ float kvb[64 * 127];   // phase1: kT[d*127+t]; phase2: v[t*64+d]
    __shared__ float hrT[64 * 64];    // [d*64+c]
    __shared__ float sw[64 * 64];     // [qloc*64+c]

    const int q0 = blockIdx.x * 64;
    const int h  = blockIdx.y;
    const int b  = blockIdx.z;
    const int tid  = threadIdx.x;
    const int lane = tid & 63;
    const int wv   = tid >> 6;        // 0..3

    // ---- stage kT[d][t] (coalesced read, scalar scattered LDS writes) ----
    {
        const int r  = tid >> 4;            // t row start
        const int c4 = (tid & 15) * 4;      // d quad
        for (int rr = r; rr < 127; rr += 16) {
            float4 kk = *(const float4*)&kv[((size_t)(b * TT + q0 + rr)) * KVN + h * DH + c4];
            kvb[(c4 + 0) * 127 + rr] = kk.x;
            kvb[(c4 + 1) * 127 + rr] = kk.y;
            kvb[(c4 + 2) * 127 + rr] = kk.z;
            kvb[(c4 + 3) * 127 + rr] = kk.w;
        }
        // hrT[d][c]
        const int rc = tid >> 2;            // c row 0..63
        const int qd = (tid & 3) * 16;      // d base
#pragma unroll
        for (int j = 0; j < 4; j++) {
            float4 hv = *(const float4*)&hr[(size_t)rc * HDIM + h * DH + qd + j * 4];
            hrT[(qd + j*4 + 0) * 64 + rc] = hv.x;
            hrT[(qd + j*4 + 1) * 64 + rc] = hv.y;
            hrT[(qd + j*4 + 2) * 64 + rc] = hv.z;
            hrT[(qd + j*4 + 3) * 64 + rc] = hv.w;
        }
    }
    __syncthreads();

    // hoist hr column for this lane (=c) into regs
    float hrv[64];
#pragma unroll
    for (int d = 0; d < 64; d++) hrv[d] = hrT[d * 64 + lane];

    // ---- scores + softmax (16 q per wave) ----
#pragma unroll 1
    for (int i = 0; i < 16; i++) {
        const int qloc = wv * 16 + i;
        const int qg   = q0 + qloc;
        // per-lane hq element; broadcast per-d via readlane
        float hqv = hq[((size_t)(b * QL + qg)) * HDIM + h * DH + lane];
        const float* kcol = &kvb[qloc + lane];
        float s0 = 0.f, s1 = 0.f, s2 = 0.f, s3 = 0.f;
#pragma unroll
        for (int d = 0; d < 64; d += 4) {
            s0 += lane_bcast(hqv, d + 0) * (kcol[(d + 0) * 127] + hrv[d + 0]);
            s1 += lane_bcast(hqv, d + 1) * (kcol[(d + 1) * 127] + hrv[d + 1]);
            s2 += lane_bcast(hqv, d + 2) * (kcol[(d + 2) * 127] + hrv[d + 2]);
            s3 += lane_bcast(hqv, d + 3) * (kcol[(d + 3) * 127] + hrv[d + 3]);
        }
        float s = ((s0 + s1) + (s2 + s3)) * 0.125f;
        if (q0 == 0) {                       // only first tile can touch t<63
            int t = qg + lane;
            if (t < 63) s += maskv[b * 64 + t];
        }
        float mx = s;
#pragma unroll
        for (int off = 32; off; off >>= 1) mx = fmaxf(mx, __shfl_xor(mx, off, 64));
        float e = __expf(s - mx);
        float sum = e;
#pragma unroll
        for (int off = 32; off; off >>= 1) sum += __shfl_xor(sum, off, 64);
        sw[qloc * 64 + lane] = e / sum;
    }
    __syncthreads();   // everyone done reading kvb (kT)

    // ---- stage v[t][d] into kvb (direct float4 writes) ----
    {
        const int r  = tid >> 4;
        const int c4 = (tid & 15) * 4;
        for (int rr = r; rr < 127; rr += 16) {
            float4 vvv = *(const float4*)&kv[((size_t)(b * TT + q0 + rr)) * KVN + HDIM + h * DH + c4];
            *(float4*)&kvb[rr * 64 + c4] = vvv;
        }
    }
    __syncthreads();

    // ---- PV: lane = d ----
#pragma unroll 1
    for (int i = 0; i < 16; i++) {
        const int qloc = wv * 16 + i;
        float wvv = sw[qloc * 64 + lane];        // own row, coalesced
        const float* vcol = &kvb[qloc * 64 + lane];
        float a0 = 0.f, a1 = 0.f, a2 = 0.f, a3 = 0.f;
#pragma unroll
        for (int c = 0; c < 64; c += 4) {
            a0 += lane_bcast(wvv, c + 0) * vcol[(c + 0) * 64];
            a1 += lane_bcast(wvv, c + 1) * vcol[(c + 1) * 64];
            a2 += lane_bcast(wvv, c + 2) * vcol[(c + 2) * 64];
            a3 += lane_bcast(wvv, c + 3) * vcol[(c + 3) * 64];
        }
        attn_out[((size_t)(b * QL + q0 + qloc)) * HDIM + h * DH + lane] = (a0 + a1) + (a2 + a3);
    }
}

// ---------------------------------------------------------------------------
extern "C" void kernel_launch(void* const* d_in, const int* in_sizes, int n_in,
                              void* d_out, int out_size, void* d_ws, size_t ws_size,
                              hipStream_t stream)
{
    const float* x   = (const float*)d_in[0];
    const float* r   = (const float*)d_in[1];
    const float* Wkv = (const float*)d_in[2];
    const float* Wq  = (const float*)d_in[3];
    const float* bq  = (const float*)d_in[4];
    const float* Wr  = (const float*)d_in[5];
    const float* Wo  = (const float*)d_in[6];
    float* out = (float*)d_out;

    float* ws = (float*)d_ws;
    float* kv_ws   = ws;                                  // 4,323,328
    float* hq_ws   = kv_ws + (size_t)BB * TT * KVN;       // 2,097,152
    float* hr_ws   = hq_ws + (size_t)BB * QL * HDIM;      // 32,768
    float* attn_ws = hr_ws + (size_t)CTX * HDIM;          // 2,097,152
    float* mask_ws = attn_ws + (size_t)BB * QL * HDIM;    // 128

    // 1) kv = x @ Wkv   [4222 x 1024 x 512]
    hipLaunchKernelGGL(gemm_bias_v2, dim3(KVN / 64, (BB * TT + 127) / 128), dim3(128), 0, stream,
                       x, Wkv, nullptr, kv_ws, BB * TT, KVN, DM, BB * TT, 0, 0);
    // 2) hq = x[:,63:] @ Wq + bq   [4096 x 512 x 512]
    hipLaunchKernelGGL(gemm_bias_v2, dim3(HDIM / 64, (BB * QL) / 128), dim3(128), 0, stream,
                       x, Wq, bq, hq_ws, BB * QL, HDIM, DM, QL, TT, CTX - 1);
    // 3) hr = r @ Wr   [64 x 512 x 512]
    hipLaunchKernelGGL(gemm_bias_v2, dim3(HDIM / 64, 1), dim3(128), 0, stream,
                       r, Wr, nullptr, hr_ws, CTX, HDIM, DM, CTX, 0, 0);
    // 4) pad mask
    hipLaunchKernelGGL(mask_kernel, dim3(CTX - 1, BB), dim3(256), 0, stream, x, mask_ws);
    // 5) fused attention
    hipLaunchKernelGGL(attn_fused, dim3(QL / 64, NH, BB), dim3(256), 0, stream,
                       kv_ws, hq_ws, hr_ws, mask_ws, attn_ws);
    // 6) out = attn @ Wo   [4096 x 512 x 512]
    hipLaunchKernelGGL(gemm_bias_v2, dim3(DM / 64, (BB * QL) / 128), dim3(128), 0, stream,
                       attn_ws, Wo, nullptr, out, BB * QL, DM, HDIM, BB * QL, 0, 0);
}

// Round 3
// 175.451 us; speedup vs baseline: 2.7187x; 2.4210x over previous
//
#include <hip/hip_runtime.h>
#include <cstdint>
#include <cstddef>

#define NH 8
#define DH 64
#define DM 512
#define CTX 64
#define BB 2
#define QL 2048
#define TT (QL + CTX - 1)   // 2111
#define HDIM 512
#define KVN 1024
#define KDIM 512            // K for all GEMMs

typedef unsigned short u16;
typedef __attribute__((ext_vector_type(8))) short bf16x8;   // 8 bf16 = 4 VGPRs
typedef __attribute__((ext_vector_type(4))) float f32x4;

__device__ __forceinline__ u16 f2bf(float f) {      // RNE float->bf16
    uint32_t u = __float_as_uint(f);
    u += 0x7FFF + ((u >> 16) & 1);
    return (u16)(u >> 16);
}
__device__ __forceinline__ float lane_bcast(float v, int l) {
    return __uint_as_float(__builtin_amdgcn_readlane(__float_as_uint(v), l));
}

#define GLLDS(g, l) __builtin_amdgcn_global_load_lds( \
    (const __attribute__((address_space(1))) void*)(g), \
    (__attribute__((address_space(3))) void*)(l), 16, 0, 0)

// ---------------------------------------------------------------------------
// cast fp32 -> bf16, 4 elems/thread
// ---------------------------------------------------------------------------
__global__ __launch_bounds__(256) void cast_bf16_vec(const float* __restrict__ src,
                                                     u16* __restrict__ dst, int n4)
{
    int i = blockIdx.x * 256 + threadIdx.x;
    if (i < n4) {
        float4 v = ((const float4*)src)[i];
        ushort4 o;
        o.x = f2bf(v.x); o.y = f2bf(v.y); o.z = f2bf(v.z); o.w = f2bf(v.w);
        ((ushort4*)dst)[i] = o;
    }
}

// ---------------------------------------------------------------------------
// W [512][N] fp32  ->  WT [N][512] bf16 (transpose + cast), 64x64 tiles
// ---------------------------------------------------------------------------
__global__ __launch_bounds__(256) void transpose_cast(const float* __restrict__ W,
                                                      u16* __restrict__ WT, int N)
{
    __shared__ float tile[64][65];
    const int tid = threadIdx.x;
    const int kb = blockIdx.y * 64, nb = blockIdx.x * 64;
    const int c4 = (tid & 15) * 4;
    for (int kk = tid >> 4; kk < 64; kk += 16) {
        float4 v = *(const float4*)&W[(size_t)(kb + kk) * N + nb + c4];
        tile[kk][c4 + 0] = v.x; tile[kk][c4 + 1] = v.y;
        tile[kk][c4 + 2] = v.z; tile[kk][c4 + 3] = v.w;
    }
    __syncthreads();
    for (int nn = tid >> 4; nn < 64; nn += 16) {
        ushort4 o;
        o.x = f2bf(tile[c4 + 0][nn]); o.y = f2bf(tile[c4 + 1][nn]);
        o.z = f2bf(tile[c4 + 2][nn]); o.w = f2bf(tile[c4 + 3][nn]);
        *(ushort4*)&WT[(size_t)(nb + nn) * KDIM + kb + c4] = o;
    }
}

// ---------------------------------------------------------------------------
// bf16 MFMA GEMM, m97 structure: 128x128 tile, BK=32, 256 threads = 4 waves,
// wave = 64x64 (4x4 of 16x16x32), global_load_lds width-16 staging.
// A [Ma][512] bf16 row-major (Ma padded to 128), BT [N][512] bf16.
// mode 0: C[M][N] fp32 (+ optional nothing).
// mode 1: h_all split epilogue: cols<1024 -> C=kv[row][1024];
//         cols>=1024 -> C2=hq[b*QL + t-63][512] + bq  (rows with t>=63 only).
// ---------------------------------------------------------------------------
__global__ __launch_bounds__(256) void gemm_mfma(
    const u16* __restrict__ A, const u16* __restrict__ BT,
    float* __restrict__ C, float* __restrict__ C2, const float* __restrict__ bq,
    int M, int N, int mode)
{
    __shared__ u16 As[128 * 32];   // [m][k] contiguous
    __shared__ u16 Bs[128 * 32];   // [n][k] contiguous

    const int tid  = threadIdx.x;
    const int lane = tid & 63;
    const int w    = tid >> 6;
    const int wm   = (w >> 1) * 64;
    const int wn   = (w & 1) * 64;
    const int m0   = blockIdx.y * 128;
    const int n0   = blockIdx.x * 128;

    // staging: chunk c = s*256 + tid covers elems c*8..c*8+7 => row c/4, koff (c%4)*8
    const int am0 = tid >> 2;           // 0..63
    const int ak0 = (tid & 3) * 8;
    const u16* ga0 = A  + (size_t)(m0 + am0) * KDIM + ak0;
    const u16* ga1 = ga0 + (size_t)64 * KDIM;
    const u16* gb0 = BT + (size_t)(n0 + am0) * KDIM + ak0;
    const u16* gb1 = gb0 + (size_t)64 * KDIM;

    f32x4 acc[4][4];
#pragma unroll
    for (int i = 0; i < 4; i++)
#pragma unroll
        for (int j = 0; j < 4; j++)
            acc[i][j] = (f32x4){0.f, 0.f, 0.f, 0.f};

    for (int kt = 0; kt < KDIM; kt += 32) {
        __syncthreads();
        GLLDS(ga0 + kt, &As[(size_t)w * 512]);
        GLLDS(ga1 + kt, &As[2048 + (size_t)w * 512]);
        GLLDS(gb0 + kt, &Bs[(size_t)w * 512]);
        GLLDS(gb1 + kt, &Bs[2048 + (size_t)w * 512]);
        __syncthreads();   // drains vmcnt: LDS tiles ready

        const int fm = lane & 15;
        const int fk = (lane >> 4) * 8;
        bf16x8 af[4], bfr[4];
#pragma unroll
        for (int i = 0; i < 4; i++)
            af[i] = *(const bf16x8*)&As[(wm + i * 16 + fm) * 32 + fk];
#pragma unroll
        for (int j = 0; j < 4; j++)
            bfr[j] = *(const bf16x8*)&Bs[(wn + j * 16 + fm) * 32 + fk];
#pragma unroll
        for (int i = 0; i < 4; i++)
#pragma unroll
            for (int j = 0; j < 4; j++)
                acc[i][j] = __builtin_amdgcn_mfma_f32_16x16x32_bf16(af[i], bfr[j], acc[i][j], 0, 0, 0);
    }

    // epilogue: C/D layout col = lane&15, row = (lane>>4)*4 + reg  [m89/m91]
    const int fc = lane & 15;
    const int fr = (lane >> 4) * 4;
    if (mode == 0) {
#pragma unroll
        for (int i = 0; i < 4; i++)
#pragma unroll
            for (int r = 0; r < 4; r++) {
                int row = m0 + wm + i * 16 + fr + r;
                if (row < M) {
#pragma unroll
                    for (int j = 0; j < 4; j++) {
                        int col = n0 + wn + j * 16 + fc;
                        C[(size_t)row * N + col] = acc[i][j][r];
                    }
                }
            }
    } else {
        const bool iskv = (n0 < 1024);   // block-uniform (1024 % 128 == 0)
#pragma unroll
        for (int i = 0; i < 4; i++)
#pragma unroll
            for (int r = 0; r < 4; r++) {
                int row = m0 + wm + i * 16 + fr + r;
                if (row < BB * TT) {
                    if (iskv) {
#pragma unroll
                        for (int j = 0; j < 4; j++) {
                            int col = n0 + wn + j * 16 + fc;
                            C[(size_t)row * KVN + col] = acc[i][j][r];
                        }
                    } else {
                        int bb = row / TT;
                        int t  = row - bb * TT;
                        if (t >= CTX - 1) {
                            size_t orow = (size_t)(bb * QL + t - (CTX - 1));
#pragma unroll
                            for (int j = 0; j < 4; j++) {
                                int col = n0 + wn + j * 16 + fc - 1024;
                                C2[orow * HDIM + col] = acc[i][j][r] + bq[col];
                            }
                        }
                    }
                }
            }
    }
}

// ---------------------------------------------------------------------------
// Pad-mask precompute: maskv[b][t] = (x[b,t,:] all zero) ? -1e30 : 0, t<63.
// ---------------------------------------------------------------------------
__global__ __launch_bounds__(256) void mask_kernel(const float* __restrict__ x,
                                                   float* __restrict__ maskv)
{
    const int t = blockIdx.x;
    const int b = blockIdx.y;
    const int i = threadIdx.x;
    const float* row = x + ((size_t)(b * TT + t)) * DM;
    bool nz = (row[i] != 0.f) || (row[i + 256] != 0.f);
    __shared__ int anyflag;
    if (i == 0) anyflag = 0;
    __syncthreads();
    unsigned long long bal = __ballot(nz);
    if ((i & 63) == 0 && bal) atomicOr(&anyflag, 1);
    __syncthreads();
    if (i == 0) maskv[b * 64 + t] = anyflag ? 0.f : -1e30f;
}

// ---------------------------------------------------------------------------
// Fused sliding-window relative attention (fp32 math, bf16 output).
// Block = (b, h, 64-q tile), 256 threads = 4 waves.
// ---------------------------------------------------------------------------
__global__ __launch_bounds__(256) void attn_fused(
    const float* __restrict__ kv,     // [B*T, 1024]
    const float* __restrict__ hq,     // [B*QL, 512]
    const float* __restrict__ hr,     // [CTX, 512]
    const float* __restrict__ maskv,  // [B, 64]
    u16* __restrict__ attnb)          // [B*QL, 512] bf16
{
    __shared__ float kvb[64 * 127];   // phase1: kT[d*127+t]; phase2: v[t*64+d]
    __shared__ float hrT[64 * 64];    // [d*64+c]
    __shared__ float sw[64 * 64];     // [qloc*64+c]

    const int q0 = blockIdx.x * 64;
    const int h  = blockIdx.y;
    const int b  = blockIdx.z;
    const int tid  = threadIdx.x;
    const int lane = tid & 63;
    const int wv   = tid >> 6;

    {
        const int r  = tid >> 4;
        const int c4 = (tid & 15) * 4;
        for (int rr = r; rr < 127; rr += 16) {
            float4 kk = *(const float4*)&kv[((size_t)(b * TT + q0 + rr)) * KVN + h * DH + c4];
            kvb[(c4 + 0) * 127 + rr] = kk.x;
            kvb[(c4 + 1) * 127 + rr] = kk.y;
            kvb[(c4 + 2) * 127 + rr] = kk.z;
            kvb[(c4 + 3) * 127 + rr] = kk.w;
        }
        const int rc = tid >> 2;
        const int qd = (tid & 3) * 16;
#pragma unroll
        for (int j = 0; j < 4; j++) {
            float4 hv = *(const float4*)&hr[(size_t)rc * HDIM + h * DH + qd + j * 4];
            hrT[(qd + j * 4 + 0) * 64 + rc] = hv.x;
            hrT[(qd + j * 4 + 1) * 64 + rc] = hv.y;
            hrT[(qd + j * 4 + 2) * 64 + rc] = hv.z;
            hrT[(qd + j * 4 + 3) * 64 + rc] = hv.w;
        }
    }
    __syncthreads();

    float hrv[64];
#pragma unroll
    for (int d = 0; d < 64; d++) hrv[d] = hrT[d * 64 + lane];

#pragma unroll 1
    for (int i = 0; i < 16; i++) {
        const int qloc = wv * 16 + i;
        const int qg   = q0 + qloc;
        float hqv = hq[((size_t)(b * QL + qg)) * HDIM + h * DH + lane];
        const float* kcol = &kvb[qloc + lane];
        float s0 = 0.f, s1 = 0.f, s2 = 0.f, s3 = 0.f;
#pragma unroll
        for (int d = 0; d < 64; d += 4) {
            s0 += lane_bcast(hqv, d + 0) * (kcol[(d + 0) * 127] + hrv[d + 0]);
            s1 += lane_bcast(hqv, d + 1) * (kcol[(d + 1) * 127] + hrv[d + 1]);
            s2 += lane_bcast(hqv, d + 2) * (kcol[(d + 2) * 127] + hrv[d + 2]);
            s3 += lane_bcast(hqv, d + 3) * (kcol[(d + 3) * 127] + hrv[d + 3]);
        }
        float s = ((s0 + s1) + (s2 + s3)) * 0.125f;
        if (q0 == 0) {
            int t = qg + lane;
            if (t < 63) s += maskv[b * 64 + t];
        }
        float mx = s;
#pragma unroll
        for (int off = 32; off; off >>= 1) mx = fmaxf(mx, __shfl_xor(mx, off, 64));
        float e = __expf(s - mx);
        float sum = e;
#pragma unroll
        for (int off = 32; off; off >>= 1) sum += __shfl_xor(sum, off, 64);
        sw[qloc * 64 + lane] = e / sum;
    }
    __syncthreads();

    {
        const int r  = tid >> 4;
        const int c4 = (tid & 15) * 4;
        for (int rr = r; rr < 127; rr += 16) {
            float4 vvv = *(const float4*)&kv[((size_t)(b * TT + q0 + rr)) * KVN + HDIM + h * DH + c4];
            *(float4*)&kvb[rr * 64 + c4] = vvv;
        }
    }
    __syncthreads();

#pragma unroll 1
    for (int i = 0; i < 16; i++) {
        const int qloc = wv * 16 + i;
        float wvv = sw[qloc * 64 + lane];
        const float* vcol = &kvb[qloc * 64 + lane];
        float a0 = 0.f, a1 = 0.f, a2 = 0.f, a3 = 0.f;
#pragma unroll
        for (int c = 0; c < 64; c += 4) {
            a0 += lane_bcast(wvv, c + 0) * vcol[(c + 0) * 64];
            a1 += lane_bcast(wvv, c + 1) * vcol[(c + 1) * 64];
            a2 += lane_bcast(wvv, c + 2) * vcol[(c + 2) * 64];
            a3 += lane_bcast(wvv, c + 3) * vcol[(c + 3) * 64];
        }
        attnb[((size_t)(b * QL + q0 + qloc)) * HDIM + h * DH + lane] = f2bf((a0 + a1) + (a2 + a3));
    }
}

// ---------------------------------------------------------------------------
extern "C" void kernel_launch(void* const* d_in, const int* in_sizes, int n_in,
                              void* d_out, int out_size, void* d_ws, size_t ws_size,
                              hipStream_t stream)
{
    const float* x   = (const float*)d_in[0];
    const float* r   = (const float*)d_in[1];
    const float* Wkv = (const float*)d_in[2];
    const float* Wq  = (const float*)d_in[3];
    const float* bq  = (const float*)d_in[4];
    const float* Wr  = (const float*)d_in[5];
    const float* Wo  = (const float*)d_in[6];
    float* out = (float*)d_out;

    char* p = (char*)d_ws;
    u16*   xb     = (u16*)p;              p += (size_t)4224 * 512 * 2;   // x bf16, padded to 4224 rows
    u16*   rb     = (u16*)p;              p += (size_t)128 * 512 * 2;    // r bf16, padded to 128 rows
    u16*   WkvqT  = (u16*)p;              p += (size_t)1536 * 512 * 2;   // [Wkv|Wq]^T bf16
    u16*   WrT    = (u16*)p;              p += (size_t)512 * 512 * 2;
    u16*   WoT    = (u16*)p;              p += (size_t)512 * 512 * 2;
    float* kv_ws  = (float*)p;            p += (size_t)BB * TT * KVN * 4;
    float* hq_ws  = (float*)p;            p += (size_t)BB * QL * HDIM * 4;
    float* hr_ws  = (float*)p;            p += (size_t)CTX * HDIM * 4;
    u16*   attnb  = (u16*)p;              p += (size_t)BB * QL * HDIM * 2;
    float* mask_ws= (float*)p;            p += 128 * 4;

    // --- prep: casts + weight transposes ---
    hipLaunchKernelGGL(cast_bf16_vec, dim3((BB * TT * DM) / 1024), dim3(256), 0, stream,
                       x, xb, (BB * TT * DM) / 4);
    hipLaunchKernelGGL(cast_bf16_vec, dim3((CTX * DM) / 1024), dim3(256), 0, stream,
                       r, rb, (CTX * DM) / 4);
    hipLaunchKernelGGL(transpose_cast, dim3(16, 8), dim3(256), 0, stream, Wkv, WkvqT, 1024);
    hipLaunchKernelGGL(transpose_cast, dim3(8, 8),  dim3(256), 0, stream, Wq,  WkvqT + (size_t)1024 * 512, 512);
    hipLaunchKernelGGL(transpose_cast, dim3(8, 8),  dim3(256), 0, stream, Wr,  WrT, 512);
    hipLaunchKernelGGL(transpose_cast, dim3(8, 8),  dim3(256), 0, stream, Wo,  WoT, 512);
    hipLaunchKernelGGL(mask_kernel, dim3(CTX - 1, BB), dim3(256), 0, stream, x, mask_ws);

    // --- G1: h_all = xb @ [Wkv|Wq]^T, split epilogue -> kv_ws, hq_ws(+bq) ---
    hipLaunchKernelGGL(gemm_mfma, dim3(1536 / 128, 33), dim3(256), 0, stream,
                       xb, WkvqT, kv_ws, hq_ws, bq, BB * TT, 1536, 1);
    // --- G3: hr = rb @ WrT ---
    hipLaunchKernelGGL(gemm_mfma, dim3(512 / 128, 1), dim3(256), 0, stream,
                       rb, WrT, hr_ws, nullptr, nullptr, CTX, HDIM, 0);
    // --- attention (fp32 math, bf16 out) ---
    hipLaunchKernelGGL(attn_fused, dim3(QL / 64, NH, BB), dim3(256), 0, stream,
                       kv_ws, hq_ws, hr_ws, mask_ws, attnb);
    // --- G2: out = attnb @ WoT ---
    hipLaunchKernelGGL(gemm_mfma, dim3(DM / 128, (BB * QL) / 128), dim3(256), 0, stream,
                       attnb, WoT, out, nullptr, nullptr, BB * QL, DM, 0);
}

// Round 4
// 160.734 us; speedup vs baseline: 2.9676x; 1.0916x over previous
//
#include <hip/hip_runtime.h>
#include <cstdint>
#include <cstddef>

#define NH 8
#define DH 64
#define DM 512
#define CTX 64
#define BB 2
#define QL 2048
#define TT (QL + CTX - 1)   // 2111
#define HDIM 512
#define KVN 1024
#define KD 512              // K for all GEMMs

typedef unsigned short u16;
typedef __attribute__((ext_vector_type(8))) short bf16x8;   // 8 bf16 = 4 VGPRs
typedef __attribute__((ext_vector_type(4))) float f32x4;

__device__ __forceinline__ u16 f2bf(float f) {      // RNE float->bf16
    uint32_t u = __float_as_uint(f);
    u += 0x7FFF + ((u >> 16) & 1);
    return (u16)(u >> 16);
}
__device__ __forceinline__ float bf2f(u16 u) {
    return __uint_as_float((uint32_t)u << 16);
}
__device__ __forceinline__ float lane_bcast(float v, int l) {
    return __uint_as_float(__builtin_amdgcn_readlane(__float_as_uint(v), l));
}

#define GLLDS(g, l) __builtin_amdgcn_global_load_lds( \
    (const __attribute__((address_space(1))) void*)(g), \
    (__attribute__((address_space(3))) void*)(l), 16, 0, 0)

// ---------------------------------------------------------------------------
// Fused prep: cast x,r -> bf16; transpose+cast Wkv,Wq,Wr,Wo; pad mask.
// Block ranges: [0,2111) x-cast | [2111,2143) r-cast | [2143,2463) transposes
//               [2463,2589) mask
// ---------------------------------------------------------------------------
__global__ __launch_bounds__(256) void prep_kernel(
    const float* __restrict__ x, const float* __restrict__ r,
    const float* __restrict__ Wkv, const float* __restrict__ Wq,
    const float* __restrict__ Wr, const float* __restrict__ Wo,
    u16* __restrict__ xb, u16* __restrict__ rb, u16* __restrict__ WkvqT,
    u16* __restrict__ WrT, u16* __restrict__ WoT, float* __restrict__ maskv)
{
    __shared__ float tile[64][65];
    __shared__ int anyflag;
    int bid = blockIdx.x;
    const int tid = threadIdx.x;

    if (bid < 2111) {                           // x cast: 4222*512/4 quads
        int i = bid * 256 + tid;
        float4 v = ((const float4*)x)[i];
        ushort4 o; o.x = f2bf(v.x); o.y = f2bf(v.y); o.z = f2bf(v.z); o.w = f2bf(v.w);
        ((ushort4*)xb)[i] = o;
        return;
    }
    bid -= 2111;
    if (bid < 32) {                             // r cast
        int i = bid * 256 + tid;
        float4 v = ((const float4*)r)[i];
        ushort4 o; o.x = f2bf(v.x); o.y = f2bf(v.y); o.z = f2bf(v.z); o.w = f2bf(v.w);
        ((ushort4*)rb)[i] = o;
        return;
    }
    bid -= 32;
    if (bid >= 320) {                           // pad mask: idx 0..125
        int idx = bid - 320;
        int t = idx >> 1, b = idx & 1;
        const float* row = x + (size_t)(b * TT + t) * DM;
        bool nz = (row[tid] != 0.f) || (row[tid + 256] != 0.f);
        if (tid == 0) anyflag = 0;
        __syncthreads();
        unsigned long long bal = __ballot(nz);
        if ((tid & 63) == 0 && bal) atomicOr(&anyflag, 1);
        __syncthreads();
        if (tid == 0) maskv[b * 64 + t] = anyflag ? 0.f : -1e30f;
        return;
    }
    // transposes
    const float* W; u16* WT; int N; int tidx;
    if (bid < 128)      { W = Wkv; WT = WkvqT;                    N = 1024; tidx = bid; }
    else if (bid < 192) { W = Wq;  WT = WkvqT + (size_t)1024*512; N = 512;  tidx = bid - 128; }
    else if (bid < 256) { W = Wr;  WT = WrT;                      N = 512;  tidx = bid - 192; }
    else                { W = Wo;  WT = WoT;                      N = 512;  tidx = bid - 256; }
    const int tpr = N / 64;
    const int kb = (tidx / tpr) * 64, nb = (tidx % tpr) * 64;
    const int c4 = (tid & 15) * 4;
    for (int kk = tid >> 4; kk < 64; kk += 16) {
        float4 v = *(const float4*)&W[(size_t)(kb + kk) * N + nb + c4];
        tile[kk][c4 + 0] = v.x; tile[kk][c4 + 1] = v.y;
        tile[kk][c4 + 2] = v.z; tile[kk][c4 + 3] = v.w;
    }
    __syncthreads();
    for (int nn = tid >> 4; nn < 64; nn += 16) {
        ushort4 o;
        o.x = f2bf(tile[c4 + 0][nn]); o.y = f2bf(tile[c4 + 1][nn]);
        o.z = f2bf(tile[c4 + 2][nn]); o.w = f2bf(tile[c4 + 3][nn]);
        *(ushort4*)&WT[(size_t)(nb + nn) * KD + kb + c4] = o;
    }
}

// ---------------------------------------------------------------------------
// bf16 MFMA GEMM 128x128 (m97 structure), bf16 outputs.
// mode 1: G1 split epilogue: cols<1024 -> kvb (bf16); cols>=1024 -> hqb+bq (bf16,
//         rows remapped t>=63). mode 2: G3, store transposed hrT[col*64+row].
// ---------------------------------------------------------------------------
__global__ __launch_bounds__(256) void gemm_mfma(
    const u16* __restrict__ A, const u16* __restrict__ BT,
    u16* __restrict__ C, u16* __restrict__ C2, const float* __restrict__ bq,
    int mode)
{
    __shared__ u16 As[128 * 32];
    __shared__ u16 Bs[128 * 32];

    const int tid  = threadIdx.x;
    const int lane = tid & 63;
    const int w    = tid >> 6;
    const int wm   = (w >> 1) * 64;
    const int wn   = (w & 1) * 64;
    const int m0   = blockIdx.y * 128;
    const int n0   = blockIdx.x * 128;

    const int am0 = tid >> 2;
    const int ak0 = (tid & 3) * 8;
    const u16* ga0 = A  + (size_t)(m0 + am0) * KD + ak0;
    const u16* ga1 = ga0 + (size_t)64 * KD;
    const u16* gb0 = BT + (size_t)(n0 + am0) * KD + ak0;
    const u16* gb1 = gb0 + (size_t)64 * KD;

    f32x4 acc[4][4];
#pragma unroll
    for (int i = 0; i < 4; i++)
#pragma unroll
        for (int j = 0; j < 4; j++)
            acc[i][j] = (f32x4){0.f, 0.f, 0.f, 0.f};

    for (int kt = 0; kt < KD; kt += 32) {
        __syncthreads();
        GLLDS(ga0 + kt, &As[(size_t)w * 512]);
        GLLDS(ga1 + kt, &As[2048 + (size_t)w * 512]);
        GLLDS(gb0 + kt, &Bs[(size_t)w * 512]);
        GLLDS(gb1 + kt, &Bs[2048 + (size_t)w * 512]);
        __syncthreads();

        const int fm = lane & 15;
        const int fk = (lane >> 4) * 8;
        bf16x8 af[4], bfr[4];
#pragma unroll
        for (int i = 0; i < 4; i++)
            af[i] = *(const bf16x8*)&As[(wm + i * 16 + fm) * 32 + fk];
#pragma unroll
        for (int j = 0; j < 4; j++)
            bfr[j] = *(const bf16x8*)&Bs[(wn + j * 16 + fm) * 32 + fk];
#pragma unroll
        for (int i = 0; i < 4; i++)
#pragma unroll
            for (int j = 0; j < 4; j++)
                acc[i][j] = __builtin_amdgcn_mfma_f32_16x16x32_bf16(af[i], bfr[j], acc[i][j], 0, 0, 0);
    }

    const int fc = lane & 15;
    const int fr = (lane >> 4) * 4;
    if (mode == 1) {
        const bool iskv = (n0 < 1024);
#pragma unroll
        for (int i = 0; i < 4; i++)
#pragma unroll
            for (int rr = 0; rr < 4; rr++) {
                int row = m0 + wm + i * 16 + fr + rr;
                if (row < BB * TT) {
                    if (iskv) {
#pragma unroll
                        for (int j = 0; j < 4; j++) {
                            int col = n0 + wn + j * 16 + fc;
                            C[(size_t)row * KVN + col] = f2bf(acc[i][j][rr]);
                        }
                    } else {
                        int bb = row / TT;
                        int t  = row - bb * TT;
                        if (t >= CTX - 1) {
                            size_t orow = (size_t)(bb * QL + t - (CTX - 1));
#pragma unroll
                            for (int j = 0; j < 4; j++) {
                                int col = n0 + wn + j * 16 + fc - 1024;
                                C2[orow * HDIM + col] = f2bf(acc[i][j][rr] + bq[col]);
                            }
                        }
                    }
                }
            }
    } else {   // mode 2: hr transposed, rows < 64
#pragma unroll
        for (int i = 0; i < 4; i++)
#pragma unroll
            for (int rr = 0; rr < 4; rr++) {
                int row = m0 + wm + i * 16 + fr + rr;
                if (row < CTX) {
#pragma unroll
                    for (int j = 0; j < 4; j++) {
                        int col = n0 + wn + j * 16 + fc;
                        C[(size_t)col * 64 + row] = f2bf(acc[i][j][rr]);
                    }
                }
            }
    }
}

// ---------------------------------------------------------------------------
// bf16 MFMA GEMM 128(M)x64(N) tiles, fp32 C — for out = attnb @ WoT (256 blocks).
// ---------------------------------------------------------------------------
__global__ __launch_bounds__(256) void gemm_n64(
    const u16* __restrict__ A, const u16* __restrict__ BT,
    float* __restrict__ C, int M, int N)
{
    __shared__ u16 As[128 * 32];
    __shared__ u16 Bs[64 * 32];

    const int tid  = threadIdx.x;
    const int lane = tid & 63;
    const int w    = tid >> 6;
    const int wm   = (w >> 1) * 64;
    const int wn   = (w & 1) * 32;
    const int m0   = blockIdx.y * 128;
    const int n0   = blockIdx.x * 64;

    const int am0 = tid >> 2;
    const int ak0 = (tid & 3) * 8;
    const u16* ga0 = A  + (size_t)(m0 + am0) * KD + ak0;
    const u16* ga1 = ga0 + (size_t)64 * KD;
    const u16* gb0 = BT + (size_t)(n0 + am0) * KD + ak0;

    f32x4 acc[4][2];
#pragma unroll
    for (int i = 0; i < 4; i++)
#pragma unroll
        for (int j = 0; j < 2; j++)
            acc[i][j] = (f32x4){0.f, 0.f, 0.f, 0.f};

    for (int kt = 0; kt < KD; kt += 32) {
        __syncthreads();
        GLLDS(ga0 + kt, &As[(size_t)w * 512]);
        GLLDS(ga1 + kt, &As[2048 + (size_t)w * 512]);
        GLLDS(gb0 + kt, &Bs[(size_t)w * 512]);
        __syncthreads();

        const int fm = lane & 15;
        const int fk = (lane >> 4) * 8;
        bf16x8 af[4], bfr[2];
#pragma unroll
        for (int i = 0; i < 4; i++)
            af[i] = *(const bf16x8*)&As[(wm + i * 16 + fm) * 32 + fk];
#pragma unroll
        for (int j = 0; j < 2; j++)
            bfr[j] = *(const bf16x8*)&Bs[(wn + j * 16 + fm) * 32 + fk];
#pragma unroll
        for (int i = 0; i < 4; i++)
#pragma unroll
            for (int j = 0; j < 2; j++)
                acc[i][j] = __builtin_amdgcn_mfma_f32_16x16x32_bf16(af[i], bfr[j], acc[i][j], 0, 0, 0);
    }

    const int fc = lane & 15;
    const int fr = (lane >> 4) * 4;
#pragma unroll
    for (int i = 0; i < 4; i++)
#pragma unroll
        for (int rr = 0; rr < 4; rr++) {
            int row = m0 + wm + i * 16 + fr + rr;
            if (row < M) {
#pragma unroll
                for (int j = 0; j < 2; j++) {
                    int col = n0 + wn + j * 16 + fc;
                    C[(size_t)row * N + col] = acc[i][j][rr];
                }
            }
        }
}

// ---------------------------------------------------------------------------
// Fused sliding-window relative attention, bf16 k/v in LDS (33.5 KB -> 4 blk/CU).
// Block = (64-q tile, h, b), 256 threads = 4 waves, 16 q per wave.
// kvls phase1: kT pairs (d-pair j: idx j*260 + t*2 + (d&1)); phase2: v[t*64+d].
// ---------------------------------------------------------------------------
__global__ __launch_bounds__(256) void attn_fused(
    const u16* __restrict__ kvb, const u16* __restrict__ hqb,
    const u16* __restrict__ hrT, const float* __restrict__ maskv,
    u16* __restrict__ attnb)
{
    __shared__ u16 kvls[8320];
    __shared__ float sw[64 * 66];

    const int q0 = blockIdx.x * 64;
    const int h  = blockIdx.y;
    const int b  = blockIdx.z;
    const int tid  = threadIdx.x;
    const int lane = tid & 63;
    const int wv   = tid >> 6;

    // ---- stage kT (bf16 d-pairs) ----
    const int r0 = tid >> 4;
    const int c4 = (tid & 15) * 4;
    const size_t kvrow0 = (size_t)(b * TT + q0);
    for (int rr = r0; rr < 127; rr += 16) {
        ushort4 kk = *(const ushort4*)&kvb[(kvrow0 + rr) * KVN + h * DH + c4];
        uint32_t p0 = (uint32_t)kk.x | ((uint32_t)kk.y << 16);
        uint32_t p1 = (uint32_t)kk.z | ((uint32_t)kk.w << 16);
        *(uint32_t*)&kvls[(c4 >> 1) * 260 + rr * 2]       = p0;
        *(uint32_t*)&kvls[((c4 >> 1) + 1) * 260 + rr * 2] = p1;
    }

    // hr column for this lane (=c): coalesced global (L2-hot, 8 KB/head)
    float hrv[64];
#pragma unroll
    for (int d = 0; d < 64; d++)
        hrv[d] = bf2f(hrT[(size_t)(h * DH + d) * 64 + lane]);

    __syncthreads();

    // ---- scores + softmax ----
#pragma unroll 1
    for (int i = 0; i < 16; i++) {
        const int qloc = wv * 16 + i;
        const int qg   = q0 + qloc;
        float hqv = bf2f(hqb[(size_t)(b * QL + qg) * HDIM + h * DH + lane]);
        const int tl2 = (qloc + lane) * 2;
        float s0 = 0.f, s1 = 0.f, s2 = 0.f, s3 = 0.f;
#pragma unroll
        for (int j = 0; j < 32; j += 2) {
            uint32_t pa = *(const uint32_t*)&kvls[j * 260 + tl2];
            uint32_t pb = *(const uint32_t*)&kvls[(j + 1) * 260 + tl2];
            s0 += lane_bcast(hqv, 2*j)     * (__uint_as_float(pa << 16)          + hrv[2*j]);
            s1 += lane_bcast(hqv, 2*j + 1) * (__uint_as_float(pa & 0xffff0000u)  + hrv[2*j + 1]);
            s2 += lane_bcast(hqv, 2*j + 2) * (__uint_as_float(pb << 16)          + hrv[2*j + 2]);
            s3 += lane_bcast(hqv, 2*j + 3) * (__uint_as_float(pb & 0xffff0000u)  + hrv[2*j + 3]);
        }
        float s = ((s0 + s1) + (s2 + s3)) * 0.125f;
        if (q0 == 0) {
            int t = qg + lane;
            if (t < 63) s += maskv[b * 64 + t];
        }
        float mx = s;
#pragma unroll
        for (int off = 32; off; off >>= 1) mx = fmaxf(mx, __shfl_xor(mx, off, 64));
        float e = __expf(s - mx);
        float sum = e;
#pragma unroll
        for (int off = 32; off; off >>= 1) sum += __shfl_xor(sum, off, 64);
        sw[qloc * 66 + lane] = e / sum;
    }
    __syncthreads();   // all waves done reading kT

    // ---- stage v[t][d] bf16 ----
    for (int rr = r0; rr < 127; rr += 16) {
        ushort4 vv = *(const ushort4*)&kvb[(kvrow0 + rr) * KVN + HDIM + h * DH + c4];
        *(ushort4*)&kvls[rr * 64 + c4] = vv;
    }
    __syncthreads();

    // ---- PV: lane = d ----
#pragma unroll 1
    for (int i = 0; i < 16; i++) {
        const int qloc = wv * 16 + i;
        float wvv = sw[qloc * 66 + lane];
        float a0 = 0.f, a1 = 0.f, a2 = 0.f, a3 = 0.f;
#pragma unroll
        for (int c = 0; c < 64; c += 4) {
            a0 += lane_bcast(wvv, c + 0) * bf2f(kvls[(qloc + c + 0) * 64 + lane]);
            a1 += lane_bcast(wvv, c + 1) * bf2f(kvls[(qloc + c + 1) * 64 + lane]);
            a2 += lane_bcast(wvv, c + 2) * bf2f(kvls[(qloc + c + 2) * 64 + lane]);
            a3 += lane_bcast(wvv, c + 3) * bf2f(kvls[(qloc + c + 3) * 64 + lane]);
        }
        attnb[(size_t)(b * QL + q0 + qloc) * HDIM + h * DH + lane] = f2bf((a0 + a1) + (a2 + a3));
    }
}

// ---------------------------------------------------------------------------
extern "C" void kernel_launch(void* const* d_in, const int* in_sizes, int n_in,
                              void* d_out, int out_size, void* d_ws, size_t ws_size,
                              hipStream_t stream)
{
    const float* x   = (const float*)d_in[0];
    const float* r   = (const float*)d_in[1];
    const float* Wkv = (const float*)d_in[2];
    const float* Wq  = (const float*)d_in[3];
    const float* bq  = (const float*)d_in[4];
    const float* Wr  = (const float*)d_in[5];
    const float* Wo  = (const float*)d_in[6];
    float* out = (float*)d_out;

    char* p = (char*)d_ws;
    u16* xb     = (u16*)p;  p += (size_t)4224 * 512 * 2;
    u16* rb     = (u16*)p;  p += (size_t)128 * 512 * 2;
    u16* WkvqT  = (u16*)p;  p += (size_t)1536 * 512 * 2;
    u16* WrT    = (u16*)p;  p += (size_t)512 * 512 * 2;
    u16* WoT    = (u16*)p;  p += (size_t)512 * 512 * 2;
    u16* kvb    = (u16*)p;  p += (size_t)4224 * 1024 * 2;
    u16* hqb    = (u16*)p;  p += (size_t)4096 * 512 * 2;
    u16* hrT    = (u16*)p;  p += (size_t)512 * 64 * 2;
    u16* attnb  = (u16*)p;  p += (size_t)4096 * 512 * 2;
    float* maskv = (float*)p;

    // 1) prep: casts, weight transposes, pad mask (2589 blocks)
    hipLaunchKernelGGL(prep_kernel, dim3(2589), dim3(256), 0, stream,
                       x, r, Wkv, Wq, Wr, Wo, xb, rb, WkvqT, WrT, WoT, maskv);
    // 2) G1: [kv|hq] = xb @ [Wkv|Wq]^T, bf16 split epilogue
    hipLaunchKernelGGL(gemm_mfma, dim3(1536 / 128, 33), dim3(256), 0, stream,
                       xb, WkvqT, kvb, hqb, bq, 1);
    // 3) G3: hrT = (rb @ WrT)^T bf16
    hipLaunchKernelGGL(gemm_mfma, dim3(512 / 128, 1), dim3(256), 0, stream,
                       rb, WrT, hrT, nullptr, nullptr, 2);
    // 4) attention
    hipLaunchKernelGGL(attn_fused, dim3(QL / 64, NH, BB), dim3(256), 0, stream,
                       kvb, hqb, hrT, maskv, attnb);
    // 5) G2: out = attnb @ WoT (128x64 tiles, 256 blocks)
    hipLaunchKernelGGL(gemm_n64, dim3(512 / 64, 4096 / 128), dim3(256), 0, stream,
                       attnb, WoT, out, 4096, 512);
}

// Round 5
// 133.598 us; speedup vs baseline: 3.5704x; 1.2031x over previous
//
#include <hip/hip_runtime.h>
#include <cstdint>
#include <cstddef>

#define NH 8
#define DH 64
#define DM 512
#define CTX 64
#define BB 2
#define QL 2048
#define TT (QL + CTX - 1)   // 2111
#define HDIM 512
#define KVN 1024
#define KD 512              // K for all GEMMs

typedef unsigned short u16;
typedef __attribute__((ext_vector_type(8))) short bf16x8;   // 8 bf16 = 4 VGPRs
typedef __attribute__((ext_vector_type(4))) float f32x4;

__device__ __forceinline__ u16 f2bf(float f) {      // RNE float->bf16
    uint32_t u = __float_as_uint(f);
    u += 0x7FFF + ((u >> 16) & 1);
    return (u16)(u >> 16);
}
__device__ __forceinline__ float bf2f(u16 u) {
    return __uint_as_float((uint32_t)u << 16);
}

#define GLLDS(g, l) __builtin_amdgcn_global_load_lds( \
    (const __attribute__((address_space(1))) void*)(g), \
    (__attribute__((address_space(3))) void*)(l), 16, 0, 0)

// ---------------------------------------------------------------------------
// Fused prep: cast x,r -> bf16; transpose+cast Wkv,Wq,Wr,Wo; pad mask.
// ---------------------------------------------------------------------------
__global__ __launch_bounds__(256) void prep_kernel(
    const float* __restrict__ x, const float* __restrict__ r,
    const float* __restrict__ Wkv, const float* __restrict__ Wq,
    const float* __restrict__ Wr, const float* __restrict__ Wo,
    u16* __restrict__ xb, u16* __restrict__ rb, u16* __restrict__ WkvqT,
    u16* __restrict__ WrT, u16* __restrict__ WoT, float* __restrict__ maskv)
{
    __shared__ float tile[64][65];
    __shared__ int anyflag;
    int bid = blockIdx.x;
    const int tid = threadIdx.x;

    if (bid < 2111) {                           // x cast
        int i = bid * 256 + tid;
        float4 v = ((const float4*)x)[i];
        ushort4 o; o.x = f2bf(v.x); o.y = f2bf(v.y); o.z = f2bf(v.z); o.w = f2bf(v.w);
        ((ushort4*)xb)[i] = o;
        return;
    }
    bid -= 2111;
    if (bid < 32) {                             // r cast
        int i = bid * 256 + tid;
        float4 v = ((const float4*)r)[i];
        ushort4 o; o.x = f2bf(v.x); o.y = f2bf(v.y); o.z = f2bf(v.z); o.w = f2bf(v.w);
        ((ushort4*)rb)[i] = o;
        return;
    }
    bid -= 32;
    if (bid >= 320) {                           // pad mask
        int idx = bid - 320;
        int t = idx >> 1, b = idx & 1;
        const float* row = x + (size_t)(b * TT + t) * DM;
        bool nz = (row[tid] != 0.f) || (row[tid + 256] != 0.f);
        if (tid == 0) anyflag = 0;
        __syncthreads();
        unsigned long long bal = __ballot(nz);
        if ((tid & 63) == 0 && bal) atomicOr(&anyflag, 1);
        __syncthreads();
        if (tid == 0) maskv[b * 64 + t] = anyflag ? 0.f : -1e30f;
        return;
    }
    // weight transposes
    const float* W; u16* WT; int N; int tidx;
    if (bid < 128)      { W = Wkv; WT = WkvqT;                    N = 1024; tidx = bid; }
    else if (bid < 192) { W = Wq;  WT = WkvqT + (size_t)1024*512; N = 512;  tidx = bid - 128; }
    else if (bid < 256) { W = Wr;  WT = WrT;                      N = 512;  tidx = bid - 192; }
    else                { W = Wo;  WT = WoT;                      N = 512;  tidx = bid - 256; }
    const int tpr = N / 64;
    const int kb = (tidx / tpr) * 64, nb = (tidx % tpr) * 64;
    const int c4 = (tid & 15) * 4;
    for (int kk = tid >> 4; kk < 64; kk += 16) {
        float4 v = *(const float4*)&W[(size_t)(kb + kk) * N + nb + c4];
        tile[kk][c4 + 0] = v.x; tile[kk][c4 + 1] = v.y;
        tile[kk][c4 + 2] = v.z; tile[kk][c4 + 3] = v.w;
    }
    __syncthreads();
    for (int nn = tid >> 4; nn < 64; nn += 16) {
        ushort4 o;
        o.x = f2bf(tile[c4 + 0][nn]); o.y = f2bf(tile[c4 + 1][nn]);
        o.z = f2bf(tile[c4 + 2][nn]); o.w = f2bf(tile[c4 + 3][nn]);
        *(ushort4*)&WT[(size_t)(nb + nn) * KD + kb + c4] = o;
    }
}

// ---------------------------------------------------------------------------
// bf16 MFMA GEMM 128x128 (m97 structure), bf16 outputs.
// mode 1: G1 split epilogue (kvb / hqb+bq remapped). mode 2: G3, standard
// row-major bf16 C[row*512+col], rows < 64.
// ---------------------------------------------------------------------------
__global__ __launch_bounds__(256) void gemm_mfma(
    const u16* __restrict__ A, const u16* __restrict__ BT,
    u16* __restrict__ C, u16* __restrict__ C2, const float* __restrict__ bq,
    int mode)
{
    __shared__ u16 As[128 * 32];
    __shared__ u16 Bs[128 * 32];

    const int tid  = threadIdx.x;
    const int lane = tid & 63;
    const int w    = tid >> 6;
    const int wm   = (w >> 1) * 64;
    const int wn   = (w & 1) * 64;
    const int m0   = blockIdx.y * 128;
    const int n0   = blockIdx.x * 128;

    const int am0 = tid >> 2;
    const int ak0 = (tid & 3) * 8;
    const u16* ga0 = A  + (size_t)(m0 + am0) * KD + ak0;
    const u16* ga1 = ga0 + (size_t)64 * KD;
    const u16* gb0 = BT + (size_t)(n0 + am0) * KD + ak0;
    const u16* gb1 = gb0 + (size_t)64 * KD;

    f32x4 acc[4][4];
#pragma unroll
    for (int i = 0; i < 4; i++)
#pragma unroll
        for (int j = 0; j < 4; j++)
            acc[i][j] = (f32x4){0.f, 0.f, 0.f, 0.f};

    for (int kt = 0; kt < KD; kt += 32) {
        __syncthreads();
        GLLDS(ga0 + kt, &As[(size_t)w * 512]);
        GLLDS(ga1 + kt, &As[2048 + (size_t)w * 512]);
        GLLDS(gb0 + kt, &Bs[(size_t)w * 512]);
        GLLDS(gb1 + kt, &Bs[2048 + (size_t)w * 512]);
        __syncthreads();

        const int fm = lane & 15;
        const int fk = (lane >> 4) * 8;
        bf16x8 af[4], bfr[4];
#pragma unroll
        for (int i = 0; i < 4; i++)
            af[i] = *(const bf16x8*)&As[(wm + i * 16 + fm) * 32 + fk];
#pragma unroll
        for (int j = 0; j < 4; j++)
            bfr[j] = *(const bf16x8*)&Bs[(wn + j * 16 + fm) * 32 + fk];
#pragma unroll
        for (int i = 0; i < 4; i++)
#pragma unroll
            for (int j = 0; j < 4; j++)
                acc[i][j] = __builtin_amdgcn_mfma_f32_16x16x32_bf16(af[i], bfr[j], acc[i][j], 0, 0, 0);
    }

    const int fc = lane & 15;
    const int fr = (lane >> 4) * 4;
    if (mode == 1) {
        const bool iskv = (n0 < 1024);
#pragma unroll
        for (int i = 0; i < 4; i++)
#pragma unroll
            for (int rr = 0; rr < 4; rr++) {
                int row = m0 + wm + i * 16 + fr + rr;
                if (row < BB * TT) {
                    if (iskv) {
#pragma unroll
                        for (int j = 0; j < 4; j++) {
                            int col = n0 + wn + j * 16 + fc;
                            C[(size_t)row * KVN + col] = f2bf(acc[i][j][rr]);
                        }
                    } else {
                        int bb = row / TT;
                        int t  = row - bb * TT;
                        if (t >= CTX - 1) {
                            size_t orow = (size_t)(bb * QL + t - (CTX - 1));
#pragma unroll
                            for (int j = 0; j < 4; j++) {
                                int col = n0 + wn + j * 16 + fc - 1024;
                                C2[orow * HDIM + col] = f2bf(acc[i][j][rr] + bq[col]);
                            }
                        }
                    }
                }
            }
    } else {   // mode 2: hr standard row-major bf16, rows < 64
#pragma unroll
        for (int i = 0; i < 4; i++)
#pragma unroll
            for (int rr = 0; rr < 4; rr++) {
                int row = m0 + wm + i * 16 + fr + rr;
                if (row < CTX) {
#pragma unroll
                    for (int j = 0; j < 4; j++) {
                        int col = n0 + wn + j * 16 + fc;
                        C[(size_t)row * HDIM + col] = f2bf(acc[i][j][rr]);
                    }
                }
            }
    }
}

// ---------------------------------------------------------------------------
// bf16 MFMA GEMM 128(M)x64(N) tiles, fp32 C — out = attnb @ WoT (256 blocks).
// ---------------------------------------------------------------------------
__global__ __launch_bounds__(256) void gemm_n64(
    const u16* __restrict__ A, const u16* __restrict__ BT,
    float* __restrict__ C, int M, int N)
{
    __shared__ u16 As[128 * 32];
    __shared__ u16 Bs[64 * 32];

    const int tid  = threadIdx.x;
    const int lane = tid & 63;
    const int w    = tid >> 6;
    const int wm   = (w >> 1) * 64;
    const int wn   = (w & 1) * 32;
    const int m0   = blockIdx.y * 128;
    const int n0   = blockIdx.x * 64;

    const int am0 = tid >> 2;
    const int ak0 = (tid & 3) * 8;
    const u16* ga0 = A  + (size_t)(m0 + am0) * KD + ak0;
    const u16* ga1 = ga0 + (size_t)64 * KD;
    const u16* gb0 = BT + (size_t)(n0 + am0) * KD + ak0;

    f32x4 acc[4][2];
#pragma unroll
    for (int i = 0; i < 4; i++)
#pragma unroll
        for (int j = 0; j < 2; j++)
            acc[i][j] = (f32x4){0.f, 0.f, 0.f, 0.f};

    for (int kt = 0; kt < KD; kt += 32) {
        __syncthreads();
        GLLDS(ga0 + kt, &As[(size_t)w * 512]);
        GLLDS(ga1 + kt, &As[2048 + (size_t)w * 512]);
        GLLDS(gb0 + kt, &Bs[(size_t)w * 512]);
        __syncthreads();

        const int fm = lane & 15;
        const int fk = (lane >> 4) * 8;
        bf16x8 af[4], bfr[2];
#pragma unroll
        for (int i = 0; i < 4; i++)
            af[i] = *(const bf16x8*)&As[(wm + i * 16 + fm) * 32 + fk];
#pragma unroll
        for (int j = 0; j < 2; j++)
            bfr[j] = *(const bf16x8*)&Bs[(wn + j * 16 + fm) * 32 + fk];
#pragma unroll
        for (int i = 0; i < 4; i++)
#pragma unroll
            for (int j = 0; j < 2; j++)
                acc[i][j] = __builtin_amdgcn_mfma_f32_16x16x32_bf16(af[i], bfr[j], acc[i][j], 0, 0, 0);
    }

    const int fc = lane & 15;
    const int fr = (lane >> 4) * 4;
#pragma unroll
    for (int i = 0; i < 4; i++)
#pragma unroll
        for (int rr = 0; rr < 4; rr++) {
            int row = m0 + wm + i * 16 + fr + rr;
            if (row < M) {
#pragma unroll
                for (int j = 0; j < 2; j++) {
                    int col = n0 + wn + j * 16 + fc;
                    C[(size_t)row * N + col] = acc[i][j][rr];
                }
            }
        }
}

// ---------------------------------------------------------------------------
// MFMA sliding-window relative attention.
// Block = (64-q tile, h, b), 4 waves; wave w owns q rows qb=q0+w*16 .. +15.
// Phase 1 (per-wave, fragments straight from global):
//   S'[16 x 80]  = hq[16x64] @ k[t=qb..qb+80)^T   (10 MFMAs)
//   S2[16 x 64]  = hq[16x64] @ hr[64x64]^T         (8 MFMAs)
// Softmax: s[m][c] = S'[m][m+c] + S2[m][c] via LDS; weights -> banded
//   W'[64 x 128] bf16 (zero-filled; row q nonzero at t_block q..q+63).
// Phase 2: O[64x64] = W' @ V[128x64] via MFMA (16 MFMAs/wave), V staged
//   transposed vT[d][136-padded] in LDS.
// LDS: sprime 20480 (aliased by vT 17408) | s2 17408 | wband 17408 = 54 KB.
// ---------------------------------------------------------------------------
__global__ __launch_bounds__(256) void attn_mfma(
    const u16* __restrict__ kvb, const u16* __restrict__ hqb,
    const u16* __restrict__ hrb, const float* __restrict__ maskv,
    u16* __restrict__ attnb)
{
    __shared__ __align__(16) char lds[55296];
    float* sprime = (float*)lds;                 // [4][16][80]
    u16*   vTs    = (u16*)lds;                   // [64][136] (aliases sprime)
    float* s2s    = (float*)(lds + 20480);       // [4][16][68]
    u16*   wband  = (u16*)(lds + 37888);         // [64][136]

    const int q0 = blockIdx.x * 64;
    const int h  = blockIdx.y;
    const int b  = blockIdx.z;
    const int tid  = threadIdx.x;
    const int lane = tid & 63;
    const int w    = tid >> 6;
    const int qb   = q0 + w * 16;

    // zero W' band buffer (64*136 u16 = 4352 u32)
    {
        uint32_t* wz = (uint32_t*)wband;
#pragma unroll
        for (int i = 0; i < 17; i++) wz[tid + i * 256] = 0;
    }
    __syncthreads();

    const int fm = lane & 15;           // m (A) / n (B) fragment index
    const int fk = (lane >> 4) * 8;     // k quad offset

    // ---- A fragments: hq rows qb+fm ----
    const u16* hqrow = hqb + (size_t)(b * QL + qb + fm) * HDIM + h * DH + fk;
    bf16x8 afr0 = *(const bf16x8*)(hqrow);
    bf16x8 afr1 = *(const bf16x8*)(hqrow + 32);

    // ---- QK': S'[16 x 80] ----
    {
        const u16* kbase = kvb + (size_t)(b * TT + qb + fm) * KVN + h * DH + fk;
#pragma unroll
        for (int nt = 0; nt < 5; nt++) {
            bf16x8 b0 = *(const bf16x8*)(kbase + (size_t)nt * 16 * KVN);
            bf16x8 b1 = *(const bf16x8*)(kbase + (size_t)nt * 16 * KVN + 32);
            f32x4 acc = (f32x4){0.f, 0.f, 0.f, 0.f};
            acc = __builtin_amdgcn_mfma_f32_16x16x32_bf16(afr0, b0, acc, 0, 0, 0);
            acc = __builtin_amdgcn_mfma_f32_16x16x32_bf16(afr1, b1, acc, 0, 0, 0);
            const int row = (lane >> 4) * 4;
#pragma unroll
            for (int r = 0; r < 4; r++)
                sprime[w * 1280 + (row + r) * 80 + nt * 16 + fm] = acc[r];
        }
    }
    // ---- S2[16 x 64] = hq @ hr^T ----
    {
        const u16* hrbase = hrb + (size_t)fm * HDIM + h * DH + fk;
#pragma unroll
        for (int nc = 0; nc < 4; nc++) {
            bf16x8 b0 = *(const bf16x8*)(hrbase + (size_t)nc * 16 * HDIM);
            bf16x8 b1 = *(const bf16x8*)(hrbase + (size_t)nc * 16 * HDIM + 32);
            f32x4 acc = (f32x4){0.f, 0.f, 0.f, 0.f};
            acc = __builtin_amdgcn_mfma_f32_16x16x32_bf16(afr0, b0, acc, 0, 0, 0);
            acc = __builtin_amdgcn_mfma_f32_16x16x32_bf16(afr1, b1, acc, 0, 0, 0);
            const int row = (lane >> 4) * 4;
#pragma unroll
            for (int r = 0; r < 4; r++)
                s2s[w * 1088 + (row + r) * 68 + nc * 16 + fm] = acc[r];
        }
    }

    // ---- softmax (per-wave; compiler inserts lgkmcnt for LDS deps) ----
#pragma unroll 1
    for (int i = 0; i < 16; i++) {
        const int qloc = w * 16 + i;
        float s = (sprime[w * 1280 + i * 80 + i + lane] +
                   s2s[w * 1088 + i * 68 + lane]) * 0.125f;
        if (q0 == 0) {
            int t = qloc + lane;
            if (t < 63) s += maskv[b * 64 + t];
        }
        float mx = s;
#pragma unroll
        for (int off = 32; off; off >>= 1) mx = fmaxf(mx, __shfl_xor(mx, off, 64));
        float e = __expf(s - mx);
        float sum = e;
#pragma unroll
        for (int off = 32; off; off >>= 1) sum += __shfl_xor(sum, off, 64);
        wband[qloc * 136 + qloc + lane] = f2bf(e / sum);
    }
    __syncthreads();   // all waves done with sprime/s2; wband complete

    // ---- stage vT[d][t_block] (overwrites sprime region) ----
    {
        const int r0 = tid >> 4;
        const int c4 = (tid & 15) * 4;
        for (int rr = r0; rr < 127; rr += 16) {
            ushort4 vv = *(const ushort4*)&kvb[(size_t)(b * TT + q0 + rr) * KVN + HDIM + h * DH + c4];
            vTs[(c4 + 0) * 136 + rr] = vv.x;
            vTs[(c4 + 1) * 136 + rr] = vv.y;
            vTs[(c4 + 2) * 136 + rr] = vv.z;
            vTs[(c4 + 3) * 136 + rr] = vv.w;
        }
        if (tid < 64) vTs[tid * 136 + 127] = 0;   // never-staged pad column
    }
    __syncthreads();

    // ---- PV: O[16 x 64] per wave = W'[16 x 128] @ V[128 x 64] ----
    f32x4 oacc[4];
#pragma unroll
    for (int j = 0; j < 4; j++) oacc[j] = (f32x4){0.f, 0.f, 0.f, 0.f};
#pragma unroll
    for (int ks = 0; ks < 4; ks++) {
        bf16x8 wa = *(const bf16x8*)&wband[(w * 16 + fm) * 136 + ks * 32 + fk];
#pragma unroll
        for (int j = 0; j < 4; j++) {
            bf16x8 vb = *(const bf16x8*)&vTs[(j * 16 + fm) * 136 + ks * 32 + fk];
            oacc[j] = __builtin_amdgcn_mfma_f32_16x16x32_bf16(wa, vb, oacc[j], 0, 0, 0);
        }
    }
    {
        const int row = (lane >> 4) * 4;
#pragma unroll
        for (int j = 0; j < 4; j++)
#pragma unroll
            for (int r = 0; r < 4; r++)
                attnb[(size_t)(b * QL + qb + row + r) * HDIM + h * DH + j * 16 + fm] =
                    f2bf(oacc[j][r]);
    }
}

// ---------------------------------------------------------------------------
extern "C" void kernel_launch(void* const* d_in, const int* in_sizes, int n_in,
                              void* d_out, int out_size, void* d_ws, size_t ws_size,
                              hipStream_t stream)
{
    const float* x   = (const float*)d_in[0];
    const float* r   = (const float*)d_in[1];
    const float* Wkv = (const float*)d_in[2];
    const float* Wq  = (const float*)d_in[3];
    const float* bq  = (const float*)d_in[4];
    const float* Wr  = (const float*)d_in[5];
    const float* Wo  = (const float*)d_in[6];
    float* out = (float*)d_out;

    char* p = (char*)d_ws;
    u16* xb     = (u16*)p;  p += (size_t)4224 * 512 * 2;
    u16* rb     = (u16*)p;  p += (size_t)128 * 512 * 2;
    u16* WkvqT  = (u16*)p;  p += (size_t)1536 * 512 * 2;
    u16* WrT    = (u16*)p;  p += (size_t)512 * 512 * 2;
    u16* WoT    = (u16*)p;  p += (size_t)512 * 512 * 2;
    u16* kvb    = (u16*)p;  p += (size_t)4224 * 1024 * 2;
    u16* hqb    = (u16*)p;  p += (size_t)4096 * 512 * 2;
    u16* hrb    = (u16*)p;  p += (size_t)64 * 512 * 2;
    u16* attnb  = (u16*)p;  p += (size_t)4096 * 512 * 2;
    float* maskv = (float*)p;

    // 1) prep: casts, weight transposes, pad mask
    hipLaunchKernelGGL(prep_kernel, dim3(2589), dim3(256), 0, stream,
                       x, r, Wkv, Wq, Wr, Wo, xb, rb, WkvqT, WrT, WoT, maskv);
    // 2) G1: [kv|hq] = xb @ [Wkv|Wq]^T, bf16 split epilogue
    hipLaunchKernelGGL(gemm_mfma, dim3(1536 / 128, 33), dim3(256), 0, stream,
                       xb, WkvqT, kvb, hqb, bq, 1);
    // 3) G3: hr = rb @ WrT (standard row-major bf16)
    hipLaunchKernelGGL(gemm_mfma, dim3(512 / 128, 1), dim3(256), 0, stream,
                       rb, WrT, hrb, nullptr, nullptr, 2);
    // 4) MFMA attention
    hipLaunchKernelGGL(attn_mfma, dim3(QL / 64, NH, BB), dim3(256), 0, stream,
                       kvb, hqb, hrb, maskv, attnb);
    // 5) G2: out = attnb @ WoT
    hipLaunchKernelGGL(gemm_n64, dim3(512 / 64, 4096 / 128), dim3(256), 0, stream,
                       attnb, WoT, out, 4096, 512);
}